// Round 4
// baseline (223.533 us; speedup 1.0000x reference)
//
#include <hip/hip_runtime.h>

#define WAYS 5
#define NSUP 25
#define NQ 30
#define HW 441
#define CH 128
#define MPAD 448
#define NWAY 2208
#define NVALID 2205
#define NCHUNKS 3
#define SUBS 23  /* 32-row sub-chunks per n-chunk */

typedef __attribute__((ext_vector_type(8))) short bh8;
typedef __attribute__((ext_vector_type(4))) float f32x4;

__device__ __forceinline__ unsigned short f2bf(float f) {
  unsigned int u = __float_as_uint(f);
  unsigned int r = (u + 0x7fffu + ((u >> 16) & 1u)) >> 16;
  return (unsigned short)r;
}

// insert b into sorted (a0 >= a1 >= a2), keep top-3.  4 VALU ops via med3.
__device__ __forceinline__ void ins3(float& a0, float& a1, float& a2, float b) {
  float u = fminf(a1, b);
  a1 = __builtin_amdgcn_fmed3f(a0, a1, b);
  a0 = fmaxf(a0, b);
  a2 = fmaxf(a2, u);
}

// ---------------- kernel 1: transpose + L2 normalize + bf16 cast ----------------
// input x[b][c][hw]; output desc[row][c] bf16 (query -> Zq, support -> Zs by way).
// Pad rows (Zq 441..447 per q, Zs 2205..2207) stay 0xAA poison: non-NaN bf16,
// masked (n-pad) or discarded (m-pad) downstream.
__global__ __launch_bounds__(256) void k_norm(const float* __restrict__ sup,
                                              const float* __restrict__ lab,
                                              const float* __restrict__ qry,
                                              unsigned short* __restrict__ Zq,
                                              unsigned short* __restrict__ Zs) {
  int img = blockIdx.x / 7;
  int chunk = blockIdx.x % 7;
  int hw0 = chunk * 64;
  int hwn = min(64, HW - hw0);
  int tid = threadIdx.x;
  __shared__ float tile[CH * 65];
  __shared__ float slab[NSUP * WAYS];
  __shared__ int sway[NSUP];
  __shared__ int s_way, s_rank;

  const float* src = (img < NSUP) ? (sup + (size_t)img * CH * HW)
                                  : (qry + (size_t)(img - NSUP) * CH * HW);
  int j = tid & 63, c0 = tid >> 6;
  if (j < hwn) {
    for (int c = c0; c < CH; c += 4)
      tile[c * 65 + j] = src[(size_t)c * HW + hw0 + j];
  }
  if (tid < NSUP * WAYS) slab[tid] = lab[tid];
  __syncthreads();
  if (tid < NSUP) {  // parallel label argmax
    int w2 = 0; float b = slab[tid * WAYS];
    for (int t = 1; t < WAYS; ++t) { float v = slab[tid * WAYS + t]; if (v > b) { b = v; w2 = t; } }
    sway[tid] = w2;
  }
  __syncthreads();
  if (tid == 0) {
    int mw = 0, r = 0;
    if (img < NSUP) {
      mw = sway[img];
      for (int s2 = 0; s2 < img; ++s2) r += (sway[s2] == mw) ? 1 : 0;
    }
    s_way = mw; s_rank = r;
  }
  __syncthreads();

  int jj = tid >> 2, qpart = tid & 3;
  int cb = qpart * 32;
  float ssum = 0.f;
  if (jj < hwn) {
    for (int c = cb; c < cb + 32; ++c) { float v = tile[c * 65 + jj]; ssum += v * v; }
  }
  ssum += __shfl_xor(ssum, 1, 64);
  ssum += __shfl_xor(ssum, 2, 64);
  float inv = 1.0f / fmaxf(sqrtf(ssum), 1e-12f);

  if (jj < hwn) {
    unsigned short* dst;
    if (img < NSUP)
      dst = Zs + ((size_t)s_way * NWAY + (size_t)s_rank * HW + hw0 + jj) * CH;
    else
      dst = Zq + ((size_t)(img - NSUP) * MPAD + hw0 + jj) * CH;
    for (int c = cb; c < cb + 32; c += 4) {
      ushort4 o;
      o.x = f2bf(tile[(c + 0) * 65 + jj] * inv);
      o.y = f2bf(tile[(c + 1) * 65 + jj] * inv);
      o.z = f2bf(tile[(c + 2) * 65 + jj] * inv);
      o.w = f2bf(tile[(c + 3) * 65 + jj] * inv);
      *(ushort4*)(dst + c) = o;
    }
  }
}

// ---------------- kernel 2: fused GEMM (mfma bf16) + per-row top-3 ----------------
// No LDS, no barriers: A-fragments read straight from L2-resident Zs; every wave
// free-runs with a 16-row register double buffer.  4 waves; mb=0 blocks cover
// m 0..255 (4 m-tiles/wave), mb=1 blocks cover m 256..447 (3 m-tiles/wave).
// D[n][m] = support . query^T ; C layout: m = lane&15, n = (lane>>4)*4 + reg.
__global__ __launch_bounds__(256, 4) void k_sim(const unsigned short* __restrict__ Zq,
                                                const unsigned short* __restrict__ Zs,
                                                float* __restrict__ part) {
  int bid = blockIdx.x;
  int cid = bid % NCHUNKS;
  int mb  = (bid / NCHUNKS) & 1;
  int w   = (bid / (NCHUNKS * 2)) % WAYS;
  int q   = bid / (NCHUNKS * 2 * WAYS);
  int tid = threadIdx.x;
  int wv = tid >> 6, l = tid & 63, lm = l & 15, lg = l >> 4;
  int nmt = 4 - mb;
  int m0 = mb ? (256 + wv * 48) : (wv * 64);

  // query fragments: up to 4 m-tiles x 4 k-steps in registers (64 VGPR)
  bh8 bfrag[4][4];
#pragma unroll
  for (int mt = 0; mt < 4; ++mt)
#pragma unroll
    for (int ks = 0; ks < 4; ++ks) {
      int mrow = min(m0 + mt * 16 + lm, MPAD - 1);  // clamp: mb=1/mt=3 unused
      bfrag[mt][ks] = *(const bh8*)(Zq + ((size_t)q * MPAD + mrow) * CH + ks * 32 + lg * 8);
    }

  float t0[4], t1[4], t2[4];
#pragma unroll
  for (int i = 0; i < 4; ++i) { t0[i] = -1e30f; t1[i] = -1e30f; t2[i] = -1e30f; }

  // A source: lane reads 16B at row*256 + (ks*4+lg)*16; bh8 index = row*16 + ks*4 + lg
  const bh8* gA = (const bh8*)(Zs + ((size_t)w * NWAY + (size_t)cid * SUBS * 32) * CH);
  int nbase0 = cid * SUBS * 32;
  const f32x4 kZ = {0.f, 0.f, 0.f, 0.f};

  auto compute = [&](const bh8 (&af)[4], int p) {
    int nbase = nbase0 + p * 16;
    bool edge = (nbase + 16 > NVALID);
#pragma unroll
    for (int mt = 0; mt < 4; ++mt) {
      if (mt < nmt) {
        f32x4 acc;
        acc = __builtin_amdgcn_mfma_f32_16x16x32_bf16(af[0], bfrag[mt][0], kZ, 0, 0, 0);
        acc = __builtin_amdgcn_mfma_f32_16x16x32_bf16(af[1], bfrag[mt][1], acc, 0, 0, 0);
        acc = __builtin_amdgcn_mfma_f32_16x16x32_bf16(af[2], bfrag[mt][2], acc, 0, 0, 0);
        acc = __builtin_amdgcn_mfma_f32_16x16x32_bf16(af[3], bfrag[mt][3], acc, 0, 0, 0);
#pragma unroll
        for (int r = 0; r < 4; ++r) {
          float v = acc[r];
          if (edge) { if (nbase + lg * 4 + r >= NVALID) v = -1e30f; }
          ins3(t0[mt], t1[mt], t2[mt], v);
        }
      }
    }
  };

  // 46 16-row phases, register double-buffered (named bufs: no runtime indexing)
  bh8 afA[4], afB[4];
#pragma unroll
  for (int ks = 0; ks < 4; ++ks) afA[ks] = gA[(size_t)lm * 16 + ks * 4 + lg];

  for (int p = 0; p < 2 * SUBS; p += 2) {
#pragma unroll
    for (int ks = 0; ks < 4; ++ks)
      afB[ks] = gA[((size_t)(p + 1) * 16 + lm) * 16 + ks * 4 + lg];
    compute(afA, p);
    if (p + 2 < 2 * SUBS) {
#pragma unroll
      for (int ks = 0; ks < 4; ++ks)
        afA[ks] = gA[((size_t)(p + 2) * 16 + lm) * 16 + ks * 4 + lg];
    }
    compute(afB, p + 1);
  }

  // merge the 4 lane-groups' partial top-3 (lanes l^16, l^32 share m = l&15)
#pragma unroll
  for (int mt = 0; mt < 4; ++mt) {
    if (mt < nmt) {
      float a0 = t0[mt], a1 = t1[mt], a2 = t2[mt];
#pragma unroll
      for (int off = 16; off <= 32; off <<= 1) {
        float b0 = __shfl_xor(a0, off, 64);
        float b1 = __shfl_xor(a1, off, 64);
        float b2 = __shfl_xor(a2, off, 64);
        ins3(a0, a1, a2, b0);
        ins3(a0, a1, a2, b1);
        ins3(a0, a1, a2, b2);
      }
      int m_local = m0 + mt * 16 + lm;
      if (lg == 0 && m_local < HW) {
        float* p = part + ((((size_t)q * WAYS + w) * NCHUNKS + cid) * HW + m_local) * 3;
        p[0] = a0; p[1] = a1; p[2] = a2;
      }
    }
  }
}

// ---------------- kernel 3: merge chunk-partial top-3s, reduce to scores ----------------
__global__ __launch_bounds__(256) void k_reduce(const float* __restrict__ part,
                                                float* __restrict__ out) {
  int qw = blockIdx.x;  // q*5 + w
  int tid = threadIdx.x;
  float sum = 0.f;
  for (int m = tid; m < HW; m += 256) {
    const float* p0 = part + ((size_t)qw * NCHUNKS) * HW * 3 + (size_t)m * 3;
    float a0 = p0[0], a1 = p0[1], a2 = p0[2];
#pragma unroll
    for (int c = 1; c < NCHUNKS; ++c) {
      const float* pc = part + ((size_t)qw * NCHUNKS + c) * HW * 3 + (size_t)m * 3;
      ins3(a0, a1, a2, pc[0]);
      ins3(a0, a1, a2, pc[1]);
      ins3(a0, a1, a2, pc[2]);
    }
    sum += a0 + a1 + a2;
  }
#pragma unroll
  for (int off = 1; off < 64; off <<= 1) sum += __shfl_xor(sum, off, 64);
  __shared__ float red[4];
  if ((tid & 63) == 0) red[tid >> 6] = sum;
  __syncthreads();
  if (tid == 0) out[qw] = (red[0] + red[1] + red[2] + red[3]) * (1.0f / 1323.0f);
}

extern "C" void kernel_launch(void* const* d_in, const int* in_sizes, int n_in,
                              void* d_out, int out_size, void* d_ws, size_t ws_size,
                              hipStream_t stream) {
  const float* sup = (const float*)d_in[0];
  const float* lab = (const float*)d_in[1];
  const float* qry = (const float*)d_in[2];
  float* out = (float*)d_out;
  char* ws = (char*)d_ws;

  unsigned short* Zq = (unsigned short*)ws;                      // 30*448*128*2  = 3,440,640 B
  unsigned short* Zs = (unsigned short*)(ws + 3440640);          // 5*2208*128*2  = 2,826,240 B
  float* part = (float*)(ws + 3440640 + 2826240);                // 150*3*441*3*4 = 2,381,400 B

  hipLaunchKernelGGL(k_norm, dim3(55 * 7), dim3(256), 0, stream, sup, lab, qry, Zq, Zs);
  hipLaunchKernelGGL(k_sim, dim3(NQ * WAYS * 2 * NCHUNKS), dim3(256), 0, stream, Zq, Zs, part);
  hipLaunchKernelGGL(k_reduce, dim3(NQ * WAYS), dim3(256), 0, stream, part, out);
}

// Round 6
// 121.828 us; speedup vs baseline: 1.8348x; 1.8348x over previous
//
#include <hip/hip_runtime.h>

#define WAYS 5
#define NSUP 25
#define NQ 30
#define HW 441
#define CH 128
#define MPAD 448
#define NWAY 2208
#define NVALID 2205
#define NCHUNKS 3
#define SUBS 23  /* 32-row sub-chunks per n-chunk */

typedef __attribute__((ext_vector_type(8))) short bh8;
typedef __attribute__((ext_vector_type(4))) float f32x4;
typedef const __attribute__((address_space(1))) unsigned int* gp1_t;
typedef __attribute__((address_space(3))) unsigned int* lp3_t;

__device__ __forceinline__ unsigned short f2bf(float f) {
  unsigned int u = __float_as_uint(f);
  unsigned int r = (u + 0x7fffu + ((u >> 16) & 1u)) >> 16;
  return (unsigned short)r;
}

// insert b into sorted (a0 >= a1 >= a2), keep top-3.  3 VALU ops:
//   a0' = max(a0,b); a1' = med3(a0,a1,b); a2' = med3(a1,a2,b)   (all from OLD values)
__device__ __forceinline__ void ins3(float& a0, float& a1, float& a2, float b) {
  float n2 = __builtin_amdgcn_fmed3f(a1, a2, b);
  float n1 = __builtin_amdgcn_fmed3f(a0, a1, b);
  a0 = fmaxf(a0, b);
  a1 = n1;
  a2 = n2;
}

// ---------------- kernel 1: transpose + L2 normalize + bf16 cast ----------------
// input x[b][c][hw]; output desc[row][c] bf16 (query -> Zq, support -> Zs by way).
// Pad rows (Zq 441..447 per q, Zs 2205..2207) stay 0xAA poison: non-NaN bf16,
// masked (n-pad) or discarded (m-pad) downstream.
__global__ __launch_bounds__(256) void k_norm(const float* __restrict__ sup,
                                              const float* __restrict__ lab,
                                              const float* __restrict__ qry,
                                              unsigned short* __restrict__ Zq,
                                              unsigned short* __restrict__ Zs) {
  int img = blockIdx.x / 7;
  int chunk = blockIdx.x % 7;
  int hw0 = chunk * 64;
  int hwn = min(64, HW - hw0);
  int tid = threadIdx.x;
  __shared__ float tile[CH * 65];
  __shared__ float slab[NSUP * WAYS];
  __shared__ int sway[NSUP];
  __shared__ int s_way, s_rank;

  const float* src = (img < NSUP) ? (sup + (size_t)img * CH * HW)
                                  : (qry + (size_t)(img - NSUP) * CH * HW);
  int j = tid & 63, c0 = tid >> 6;
  if (j < hwn) {
    for (int c = c0; c < CH; c += 4)
      tile[c * 65 + j] = src[(size_t)c * HW + hw0 + j];
  }
  if (tid < NSUP * WAYS) slab[tid] = lab[tid];
  __syncthreads();
  if (tid < NSUP) {  // parallel label argmax
    int w2 = 0; float b = slab[tid * WAYS];
    for (int t = 1; t < WAYS; ++t) { float v = slab[tid * WAYS + t]; if (v > b) { b = v; w2 = t; } }
    sway[tid] = w2;
  }
  __syncthreads();
  if (tid == 0) {
    int mw = 0, r = 0;
    if (img < NSUP) {
      mw = sway[img];
      for (int s2 = 0; s2 < img; ++s2) r += (sway[s2] == mw) ? 1 : 0;
    }
    s_way = mw; s_rank = r;
  }
  __syncthreads();

  int jj = tid >> 2, qpart = tid & 3;
  int cb = qpart * 32;
  float ssum = 0.f;
  if (jj < hwn) {
    for (int c = cb; c < cb + 32; ++c) { float v = tile[c * 65 + jj]; ssum += v * v; }
  }
  ssum += __shfl_xor(ssum, 1, 64);
  ssum += __shfl_xor(ssum, 2, 64);
  float inv = 1.0f / fmaxf(sqrtf(ssum), 1e-12f);

  if (jj < hwn) {
    unsigned short* dst;
    if (img < NSUP)
      dst = Zs + ((size_t)s_way * NWAY + (size_t)s_rank * HW + hw0 + jj) * CH;
    else
      dst = Zq + ((size_t)(img - NSUP) * MPAD + hw0 + jj) * CH;
    for (int c = cb; c < cb + 32; c += 4) {
      ushort4 o;
      o.x = f2bf(tile[(c + 0) * 65 + jj] * inv);
      o.y = f2bf(tile[(c + 1) * 65 + jj] * inv);
      o.z = f2bf(tile[(c + 2) * 65 + jj] * inv);
      o.w = f2bf(tile[(c + 3) * 65 + jj] * inv);
      *(ushort4*)(dst + c) = o;
    }
  }
}

// ---------------- kernel 2: fused GEMM (mfma bf16) + per-row top-3 ----------------
// block = (q, way, m-block, n-chunk); 4 waves; mb=0 covers m 0..255 (4 mt/wave),
// mb=1 covers m 256..447 (3 mt/wave).  Support staged via global_load_lds
// (width 16), swizzle on the GLOBAL source address, LDS dest linear:
//   lds[row][c2] = Zs_sub[row][c2 ^ (row&7)]   (16B chunks)
// D[n][m] = support . query^T ; C layout: m = lane&15, n = (lane>>4)*4 + reg.
__global__ __launch_bounds__(256, 4) void k_sim(const unsigned short* __restrict__ Zq,
                                                const unsigned short* __restrict__ Zs,
                                                float* __restrict__ part) {
  int bid = blockIdx.x;
  int cid = bid % NCHUNKS;
  int mb  = (bid / NCHUNKS) & 1;
  int w   = (bid / (NCHUNKS * 2)) % WAYS;
  int q   = bid / (NCHUNKS * 2 * WAYS);
  int tid = threadIdx.x;
  int wv = tid >> 6, l = tid & 63, lm = l & 15, lg = l >> 4;
  int nmt = 4 - mb;
  int m0 = mb ? (256 + wv * 48) : (wv * 64);
  __shared__ __align__(16) unsigned short sbuf[2][32 * CH];  // 2 x 8192 B

  // query fragments: up to 4 m-tiles x 4 k-steps in registers
  bh8 bfrag[4][4];
#pragma unroll
  for (int mt = 0; mt < 4; ++mt)
#pragma unroll
    for (int ks = 0; ks < 4; ++ks) {
      int mrow = min(m0 + mt * 16 + lm, MPAD - 1);  // clamp: mb=1/mt=3 unused
      bfrag[mt][ks] = *(const bh8*)(Zq + ((size_t)q * MPAD + mrow) * CH + ks * 32 + lg * 8);
    }

  float t0[4], t1[4], t2[4];
#pragma unroll
  for (int i = 0; i < 4; ++i) { t0[i] = -1e30f; t1[i] = -1e30f; t2[i] = -1e30f; }

  // per-lane pre-swizzled global source: row_l = wv*4 + (l>>4), chunk (l&15)^(row_l&7)
  int row_l = wv * 4 + (l >> 4);
  int swz = (l & 15) ^ (row_l & 7);
  const char* gsrc = (const char*)(Zs + ((size_t)w * NWAY + (size_t)cid * SUBS * 32) * CH)
                     + row_l * 256 + swz * 16;
  char* lbase = (char*)&sbuf[0][0] + wv * 1024;  // wave-uniform

  // per-ks LDS read vaddr (XOR swizzle folded in once; row&7 == lm&7 for all tl)
  const char* lrd[4];
#pragma unroll
  for (int ks = 0; ks < 4; ++ks)
    lrd[ks] = (const char*)(&sbuf[0][0]) + lm * 256 + (((ks * 4 + lg) ^ (lm & 7)) * 16);

  int nbase0 = cid * SUBS * 32;
  const f32x4 kZ = {0.f, 0.f, 0.f, 0.f};

  // prologue: stage sub-chunk 0 into buf 0
  __builtin_amdgcn_global_load_lds((gp1_t)(gsrc), (lp3_t)(lbase), 16, 0, 0);
  __builtin_amdgcn_global_load_lds((gp1_t)(gsrc + 4096), (lp3_t)(lbase + 4096), 16, 0, 0);
  __syncthreads();

  bool anyedge_c = (cid == NCHUNKS - 1);

  for (int s = 0; s < SUBS; ++s) {
    int cur = s & 1;
    if (s + 1 < SUBS) {  // issue next sub-chunk into the dead buffer
      const char* g = gsrc + (size_t)(s + 1) * 8192;
      char* lb = lbase + (cur ^ 1) * 8192;
      __builtin_amdgcn_global_load_lds((gp1_t)(g), (lp3_t)(lb), 16, 0, 0);
      __builtin_amdgcn_global_load_lds((gp1_t)(g + 4096), (lp3_t)(lb + 4096), 16, 0, 0);
    }
    bool anyedge = anyedge_c && (s == SUBS - 1);
#pragma unroll
    for (int tl = 0; tl < 2; ++tl) {
      bh8 af[4];
#pragma unroll
      for (int ks = 0; ks < 4; ++ks)
        af[ks] = *(const bh8*)(lrd[ks] + cur * 8192 + tl * 4096);  // buf stride 8192 B
#pragma unroll
      for (int mt = 0; mt < 4; ++mt) {
        if (mt < nmt) {
          f32x4 acc;
          acc = __builtin_amdgcn_mfma_f32_16x16x32_bf16(af[0], bfrag[mt][0], kZ, 0, 0, 0);
          acc = __builtin_amdgcn_mfma_f32_16x16x32_bf16(af[1], bfrag[mt][1], acc, 0, 0, 0);
          acc = __builtin_amdgcn_mfma_f32_16x16x32_bf16(af[2], bfrag[mt][2], acc, 0, 0, 0);
          acc = __builtin_amdgcn_mfma_f32_16x16x32_bf16(af[3], bfrag[mt][3], acc, 0, 0, 0);
          if (anyedge && tl == 1) {  // wave-uniform rare path: mask n-pad rows
            int nbase = nbase0 + s * 32 + 16;
#pragma unroll
            for (int r = 0; r < 4; ++r) {
              float v = (nbase + lg * 4 + r >= NVALID) ? -1e30f : acc[r];
              ins3(t0[mt], t1[mt], t2[mt], v);
            }
          } else {
#pragma unroll
            for (int r = 0; r < 4; ++r) ins3(t0[mt], t1[mt], t2[mt], acc[r]);
          }
        }
      }
    }
    __syncthreads();  // drains vmcnt -> next buffer ready; protects buf reuse
  }

  // merge the 4 lane-groups' partial top-3 (lanes l^16, l^32 share m = l&15)
#pragma unroll
  for (int mt = 0; mt < 4; ++mt) {
    if (mt < nmt) {
      float a0 = t0[mt], a1 = t1[mt], a2 = t2[mt];
#pragma unroll
      for (int off = 16; off <= 32; off <<= 1) {
        float b0 = __shfl_xor(a0, off, 64);
        float b1 = __shfl_xor(a1, off, 64);
        float b2 = __shfl_xor(a2, off, 64);
        ins3(a0, a1, a2, b0);
        ins3(a0, a1, a2, b1);
        ins3(a0, a1, a2, b2);
      }
      int m_local = m0 + mt * 16 + lm;
      if (lg == 0 && m_local < HW) {
        float* p = part + ((((size_t)q * WAYS + w) * NCHUNKS + cid) * HW + m_local) * 3;
        p[0] = a0; p[1] = a1; p[2] = a2;
      }
    }
  }
}

// ---------------- kernel 3: merge chunk-partial top-3s, reduce to scores ----------------
__global__ __launch_bounds__(256) void k_reduce(const float* __restrict__ part,
                                                float* __restrict__ out) {
  int qw = blockIdx.x;  // q*5 + w
  int tid = threadIdx.x;
  float sum = 0.f;
  for (int m = tid; m < HW; m += 256) {
    const float* p0 = part + ((size_t)qw * NCHUNKS) * HW * 3 + (size_t)m * 3;
    float a0 = p0[0], a1 = p0[1], a2 = p0[2];
#pragma unroll
    for (int c = 1; c < NCHUNKS; ++c) {
      const float* pc = part + ((size_t)qw * NCHUNKS + c) * HW * 3 + (size_t)m * 3;
      ins3(a0, a1, a2, pc[0]);
      ins3(a0, a1, a2, pc[1]);
      ins3(a0, a1, a2, pc[2]);
    }
    sum += a0 + a1 + a2;
  }
#pragma unroll
  for (int off = 1; off < 64; off <<= 1) sum += __shfl_xor(sum, off, 64);
  __shared__ float red[4];
  if ((tid & 63) == 0) red[tid >> 6] = sum;
  __syncthreads();
  if (tid == 0) out[qw] = (red[0] + red[1] + red[2] + red[3]) * (1.0f / 1323.0f);
}

extern "C" void kernel_launch(void* const* d_in, const int* in_sizes, int n_in,
                              void* d_out, int out_size, void* d_ws, size_t ws_size,
                              hipStream_t stream) {
  const float* sup = (const float*)d_in[0];
  const float* lab = (const float*)d_in[1];
  const float* qry = (const float*)d_in[2];
  float* out = (float*)d_out;
  char* ws = (char*)d_ws;

  unsigned short* Zq = (unsigned short*)ws;                      // 30*448*128*2  = 3,440,640 B
  unsigned short* Zs = (unsigned short*)(ws + 3440640);          // 5*2208*128*2  = 2,826,240 B
  float* part = (float*)(ws + 3440640 + 2826240);                // 150*3*441*3*4 = 2,381,400 B

  hipLaunchKernelGGL(k_norm, dim3(55 * 7), dim3(256), 0, stream, sup, lab, qry, Zq, Zs);
  hipLaunchKernelGGL(k_sim, dim3(NQ * WAYS * 2 * NCHUNKS), dim3(256), 0, stream, Zq, Zs, part);
  hipLaunchKernelGGL(k_reduce, dim3(NQ * WAYS), dim3(256), 0, stream, part, out);
}

// Round 8
// 118.830 us; speedup vs baseline: 1.8811x; 1.0252x over previous
//
#include <hip/hip_runtime.h>

#define WAYS 5
#define NSUP 25
#define NQ 30
#define HW 441
#define CH 128
#define MPAD 448
#define NWAY 2208
#define NVALID 2205
#define NCHUNKS 3
#define SUBS 23  /* 32-row sub-chunks per n-chunk */

typedef __attribute__((ext_vector_type(8))) short bh8;
typedef __attribute__((ext_vector_type(4))) float f32x4;
typedef const __attribute__((address_space(1))) unsigned int* gp1_t;
typedef __attribute__((address_space(3))) unsigned int* lp3_t;

__device__ __forceinline__ unsigned short f2bf(float f) {
  unsigned int u = __float_as_uint(f);
  unsigned int r = (u + 0x7fffu + ((u >> 16) & 1u)) >> 16;
  return (unsigned short)r;
}

// insert b into sorted (a0 >= a1 >= a2), keep top-3.  3 VALU ops:
//   a0' = max(a0,b); a1' = med3(a0,a1,b); a2' = med3(a1,a2,b)   (all from OLD values)
__device__ __forceinline__ void ins3(float& a0, float& a1, float& a2, float b) {
  float n2 = __builtin_amdgcn_fmed3f(a1, a2, b);
  float n1 = __builtin_amdgcn_fmed3f(a0, a1, b);
  a0 = fmaxf(a0, b);
  a1 = n1;
  a2 = n2;
}

// ---------------- kernel 1: transpose + L2 normalize + bf16 cast ----------------
__global__ __launch_bounds__(256) void k_norm(const float* __restrict__ sup,
                                              const float* __restrict__ lab,
                                              const float* __restrict__ qry,
                                              unsigned short* __restrict__ Zq,
                                              unsigned short* __restrict__ Zs) {
  int img = blockIdx.x / 7;
  int chunk = blockIdx.x % 7;
  int hw0 = chunk * 64;
  int hwn = min(64, HW - hw0);
  int tid = threadIdx.x;
  __shared__ float tile[CH * 65];
  __shared__ float slab[NSUP * WAYS];
  __shared__ int sway[NSUP];
  __shared__ int s_way, s_rank;

  const float* src = (img < NSUP) ? (sup + (size_t)img * CH * HW)
                                  : (qry + (size_t)(img - NSUP) * CH * HW);
  int j = tid & 63, c0 = tid >> 6;
  if (j < hwn) {
    for (int c = c0; c < CH; c += 4)
      tile[c * 65 + j] = src[(size_t)c * HW + hw0 + j];
  }
  if (tid < NSUP * WAYS) slab[tid] = lab[tid];
  __syncthreads();
  if (tid < NSUP) {  // parallel label argmax
    int w2 = 0; float b = slab[tid * WAYS];
    for (int t = 1; t < WAYS; ++t) { float v = slab[tid * WAYS + t]; if (v > b) { b = v; w2 = t; } }
    sway[tid] = w2;
  }
  __syncthreads();
  if (tid == 0) {
    int mw = 0, r = 0;
    if (img < NSUP) {
      mw = sway[img];
      for (int s2 = 0; s2 < img; ++s2) r += (sway[s2] == mw) ? 1 : 0;
    }
    s_way = mw; s_rank = r;
  }
  __syncthreads();

  int jj = tid >> 2, qpart = tid & 3;
  int cb = qpart * 32;
  float ssum = 0.f;
  if (jj < hwn) {
    for (int c = cb; c < cb + 32; ++c) { float v = tile[c * 65 + jj]; ssum += v * v; }
  }
  ssum += __shfl_xor(ssum, 1, 64);
  ssum += __shfl_xor(ssum, 2, 64);
  float inv = 1.0f / fmaxf(sqrtf(ssum), 1e-12f);

  if (jj < hwn) {
    unsigned short* dst;
    if (img < NSUP)
      dst = Zs + ((size_t)s_way * NWAY + (size_t)s_rank * HW + hw0 + jj) * CH;
    else
      dst = Zq + ((size_t)(img - NSUP) * MPAD + hw0 + jj) * CH;
    for (int c = cb; c < cb + 32; c += 4) {
      ushort4 o;
      o.x = f2bf(tile[(c + 0) * 65 + jj] * inv);
      o.y = f2bf(tile[(c + 1) * 65 + jj] * inv);
      o.z = f2bf(tile[(c + 2) * 65 + jj] * inv);
      o.w = f2bf(tile[(c + 3) * 65 + jj] * inv);
      *(ushort4*)(dst + c) = o;
    }
  }
}

// ---------------- kernel 2: fused GEMM (mfma bf16) + per-row top-3 ----------------
// block = (q, way, m-block, n-chunk); 4 waves; mb=0 covers m 0..255 (4 mt/wave),
// mb=1 covers m 256..447 (3 mt/wave).  Support staged via global_load_lds
// (width 16), FULL 4-bit XOR swizzle on the GLOBAL source address, LDS linear:
//   lds[row][c2] = Zs_sub[row][c2 ^ (row&15)]   (16B chunks)
// D[n][m] = support . query^T ; C layout: m = lane&15, n = (lane>>4)*4 + reg.
__global__ __launch_bounds__(256, 4) void k_sim(const unsigned short* __restrict__ Zq,
                                                const unsigned short* __restrict__ Zs,
                                                float* __restrict__ part) {
  int bid = blockIdx.x;
  int cid = bid % NCHUNKS;
  int mb  = (bid / NCHUNKS) & 1;
  int w   = (bid / (NCHUNKS * 2)) % WAYS;
  int q   = bid / (NCHUNKS * 2 * WAYS);
  int tid = threadIdx.x;
  int wv = tid >> 6, l = tid & 63, lm = l & 15, lg = l >> 4;
  int nmt = 4 - mb;
  int m0 = mb ? (256 + wv * 48) : (wv * 64);
  __shared__ __align__(16) unsigned short sbuf[2][32 * CH];  // 2 x 8192 B

  // query fragments: up to 4 m-tiles x 4 k-steps in registers
  bh8 bfrag[4][4];
#pragma unroll
  for (int mt = 0; mt < 4; ++mt)
#pragma unroll
    for (int ks = 0; ks < 4; ++ks) {
      int mrow = min(m0 + mt * 16 + lm, MPAD - 1);  // clamp: mb=1/mt=3 unused
      bfrag[mt][ks] = *(const bh8*)(Zq + ((size_t)q * MPAD + mrow) * CH + ks * 32 + lg * 8);
    }
  // pin MFMA operands to ARCH VGPRs (forbid AGPR banishment -> no accvgpr copies,
  // unified reg total <= 128 so 4 waves/SIMD can be resident)
#pragma unroll
  for (int mt = 0; mt < 4; ++mt)
#pragma unroll
    for (int ks = 0; ks < 4; ++ks)
      asm volatile("" : "+v"(bfrag[mt][ks]));

  float t0[4], t1[4], t2[4];
#pragma unroll
  for (int i = 0; i < 4; ++i) { t0[i] = -1e30f; t1[i] = -1e30f; t2[i] = -1e30f; }

  // per-lane pre-swizzled global source: row_l = wv*4 + lg in 0..15; full 4-bit XOR
  int row_l = wv * 4 + lg;
  int swz = (l & 15) ^ row_l;
  const char* gsrc = (const char*)(Zs + ((size_t)w * NWAY + (size_t)cid * SUBS * 32) * CH)
                     + row_l * 256 + swz * 16;
  char* lbase = (char*)&sbuf[0][0] + wv * 1024;  // wave-uniform

  // per-ks LDS read element offsets (ushort units); row = tl*16+lm -> row&15 == lm
  int idx0[4];
#pragma unroll
  for (int ks = 0; ks < 4; ++ks)
    idx0[ks] = lm * 128 + (((ks * 4 + lg) ^ lm) * 8);

  int nbase0 = cid * SUBS * 32;
  const f32x4 kZ = {0.f, 0.f, 0.f, 0.f};

  // prologue: stage sub-chunk 0 into buf 0
  __builtin_amdgcn_global_load_lds((gp1_t)(gsrc), (lp3_t)(lbase), 16, 0, 0);
  __builtin_amdgcn_global_load_lds((gp1_t)(gsrc + 4096), (lp3_t)(lbase + 4096), 16, 0, 0);
  __syncthreads();

  bool anyedge_c = (cid == NCHUNKS - 1);

  for (int s = 0; s < SUBS; ++s) {
    int cur = s & 1;
    if (s + 1 < SUBS) {  // issue next sub-chunk into the dead buffer
      const char* g = gsrc + (size_t)(s + 1) * 8192;
      char* lb = lbase + (cur ^ 1) * 8192;
      __builtin_amdgcn_global_load_lds((gp1_t)(g), (lp3_t)(lb), 16, 0, 0);
      __builtin_amdgcn_global_load_lds((gp1_t)(g + 4096), (lp3_t)(lb + 4096), 16, 0, 0);
    }
    bool anyedge = anyedge_c && (s == SUBS - 1);
#pragma unroll
    for (int tl = 0; tl < 2; ++tl) {
      bh8 af[4];
#pragma unroll
      for (int ks = 0; ks < 4; ++ks)
        af[ks] = *(const bh8*)&sbuf[cur][idx0[ks] + tl * 2048];
#pragma unroll
      for (int mt = 0; mt < 4; ++mt) {
        if (mt < nmt) {
          f32x4 acc;
          acc = __builtin_amdgcn_mfma_f32_16x16x32_bf16(af[0], bfrag[mt][0], kZ, 0, 0, 0);
          acc = __builtin_amdgcn_mfma_f32_16x16x32_bf16(af[1], bfrag[mt][1], acc, 0, 0, 0);
          acc = __builtin_amdgcn_mfma_f32_16x16x32_bf16(af[2], bfrag[mt][2], acc, 0, 0, 0);
          acc = __builtin_amdgcn_mfma_f32_16x16x32_bf16(af[3], bfrag[mt][3], acc, 0, 0, 0);
          if (anyedge && tl == 1) {  // wave-uniform rare path: mask n-pad rows
            int nbase = nbase0 + s * 32 + 16;
#pragma unroll
            for (int r = 0; r < 4; ++r) {
              float v = (nbase + lg * 4 + r >= NVALID) ? -1e30f : acc[r];
              ins3(t0[mt], t1[mt], t2[mt], v);
            }
          } else {
#pragma unroll
            for (int r = 0; r < 4; ++r) ins3(t0[mt], t1[mt], t2[mt], acc[r]);
          }
        }
      }
    }
    __syncthreads();  // drains vmcnt -> next buffer ready; protects buf reuse
  }

  // merge the 4 lane-groups' partial top-3 (lanes l^16, l^32 share m = l&15)
#pragma unroll
  for (int mt = 0; mt < 4; ++mt) {
    if (mt < nmt) {
      float a0 = t0[mt], a1 = t1[mt], a2 = t2[mt];
#pragma unroll
      for (int off = 16; off <= 32; off <<= 1) {
        float b0 = __shfl_xor(a0, off, 64);
        float b1 = __shfl_xor(a1, off, 64);
        float b2 = __shfl_xor(a2, off, 64);
        ins3(a0, a1, a2, b0);
        ins3(a0, a1, a2, b1);
        ins3(a0, a1, a2, b2);
      }
      int m_local = m0 + mt * 16 + lm;
      if (lg == 0 && m_local < HW) {
        float* p = part + ((((size_t)q * WAYS + w) * NCHUNKS + cid) * HW + m_local) * 3;
        p[0] = a0; p[1] = a1; p[2] = a2;
      }
    }
  }
}

// ---------------- kernel 3: merge chunk-partial top-3s, reduce to scores ----------------
__global__ __launch_bounds__(256) void k_reduce(const float* __restrict__ part,
                                                float* __restrict__ out) {
  int qw = blockIdx.x;  // q*5 + w
  int tid = threadIdx.x;
  float sum = 0.f;
  for (int m = tid; m < HW; m += 256) {
    const float* p0 = part + ((size_t)qw * NCHUNKS) * HW * 3 + (size_t)m * 3;
    float a0 = p0[0], a1 = p0[1], a2 = p0[2];
#pragma unroll
    for (int c = 1; c < NCHUNKS; ++c) {
      const float* pc = part + ((size_t)qw * NCHUNKS + c) * HW * 3 + (size_t)m * 3;
      ins3(a0, a1, a2, pc[0]);
      ins3(a0, a1, a2, pc[1]);
      ins3(a0, a1, a2, pc[2]);
    }
    sum += a0 + a1 + a2;
  }
#pragma unroll
  for (int off = 1; off < 64; off <<= 1) sum += __shfl_xor(sum, off, 64);
  __shared__ float red[4];
  if ((tid & 63) == 0) red[tid >> 6] = sum;
  __syncthreads();
  if (tid == 0) out[qw] = (red[0] + red[1] + red[2] + red[3]) * (1.0f / 1323.0f);
}

extern "C" void kernel_launch(void* const* d_in, const int* in_sizes, int n_in,
                              void* d_out, int out_size, void* d_ws, size_t ws_size,
                              hipStream_t stream) {
  const float* sup = (const float*)d_in[0];
  const float* lab = (const float*)d_in[1];
  const float* qry = (const float*)d_in[2];
  float* out = (float*)d_out;
  char* ws = (char*)d_ws;

  unsigned short* Zq = (unsigned short*)ws;                      // 30*448*128*2  = 3,440,640 B
  unsigned short* Zs = (unsigned short*)(ws + 3440640);          // 5*2208*128*2  = 2,826,240 B
  float* part = (float*)(ws + 3440640 + 2826240);                // 150*3*441*3*4 = 2,381,400 B

  hipLaunchKernelGGL(k_norm, dim3(55 * 7), dim3(256), 0, stream, sup, lab, qry, Zq, Zs);
  hipLaunchKernelGGL(k_sim, dim3(NQ * WAYS * 2 * NCHUNKS), dim3(256), 0, stream, Zq, Zs, part);
  hipLaunchKernelGGL(k_reduce, dim3(NQ * WAYS), dim3(256), 0, stream, part, out);
}